// Round 4
// baseline (756.110 us; speedup 1.0000x reference)
//
#include <hip/hip_runtime.h>
#include <hip/hip_bf16.h>
#include <stdint.h>
#include <math.h>

#define T_TOK 8192
#define DDIM  1024
#define HDIM  512
#define NEXP  64
#define TOPK  8
#define CHUNKS 16

typedef __bf16 bf16x8 __attribute__((ext_vector_type(8)));
typedef float  f32x4  __attribute__((ext_vector_type(4)));

__device__ __forceinline__ void load_lds16(const void* gp, void* lp){
  __builtin_amdgcn_global_load_lds(
      (__attribute__((address_space(1))) void*)(uintptr_t)gp,
      (__attribute__((address_space(3))) void*)lp, 16, 0, 0);
}

__device__ __forceinline__ unsigned short f2bfbits(float f){
  union { __bf16 b; unsigned short u; } cv; cv.b = (__bf16)f; return cv.u;
}
__device__ __forceinline__ float bf2f(unsigned short s){
  unsigned int u = ((unsigned int)s) << 16; return __uint_as_float(u);
}

// ---------------- x -> bf16 ----------------
__global__ __launch_bounds__(256) void k_cvt_x(const float* __restrict__ x,
                                               __bf16* __restrict__ xb){
  size_t i   = (size_t)blockIdx.x * 256 + threadIdx.x;
  size_t off = i * 8;
  float4 v0 = *(const float4*)(x + off);
  float4 v1 = *(const float4*)(x + off + 4);
  bf16x8 o;
  o[0]=(__bf16)v0.x; o[1]=(__bf16)v0.y; o[2]=(__bf16)v0.z; o[3]=(__bf16)v0.w;
  o[4]=(__bf16)v1.x; o[5]=(__bf16)v1.y; o[6]=(__bf16)v1.z; o[7]=(__bf16)v1.w;
  *(bf16x8*)(xb + off) = o;
}

// ------- transpose + convert: src [z][R][C] f32 -> dst [z][C][R] bf16 -------
__global__ __launch_bounds__(256) void k_transpose_cvt(const float* __restrict__ src,
                                                       __bf16* __restrict__ dst,
                                                       int R, int C){
  __shared__ float tile[32][33];
  int z  = blockIdx.z;
  int c0 = blockIdx.x * 32;
  int r0 = blockIdx.y * 32;
  const float* s = src + (size_t)z * R * C;
  __bf16*      d = dst + (size_t)z * R * C;
  int tx = threadIdx.x, ty = threadIdx.y;
  #pragma unroll
  for (int i = ty; i < 32; i += 8)
    tile[i][tx] = s[(size_t)(r0 + i) * C + c0 + tx];
  __syncthreads();
  #pragma unroll
  for (int i = ty; i < 32; i += 8)
    d[(size_t)(c0 + i) * R + r0 + tx] = (__bf16)tile[tx][i];
}

// ---------------- gate GEMM: logits[T][64] (f64 accumulate) ----------------
__global__ __launch_bounds__(256) void k_gate(const float* __restrict__ x,
                                              const float* __restrict__ Wg,
                                              float* __restrict__ logits){
  __shared__ float xs[32][64];
  __shared__ float ws[32][64];
  const int tid = threadIdx.x;
  const int m0  = blockIdx.x * 64;
  const int tm  = (tid >> 4) << 2;
  const int tn  = (tid & 15) << 2;
  const int sr  = tid >> 2;
  const int sc  = tid & 3;
  double acc[4][4];
  #pragma unroll
  for (int i=0;i<4;i++)
    #pragma unroll
    for (int j=0;j<4;j++) acc[i][j]=0.0;

  for (int k0 = 0; k0 < DDIM; k0 += 32){
    {
      const float4* g = (const float4*)(Wg + (size_t)k0 * 64);
      float4* l = (float4*)&ws[0][0];
      l[tid]       = g[tid];
      l[tid + 256] = g[tid + 256];
    }
    {
      const float* g = x + (size_t)(m0 + sr) * DDIM + k0 + sc * 8;
      float4 a = *(const float4*)g;
      float4 b = *(const float4*)(g + 4);
      xs[sc*8+0][sr]=a.x; xs[sc*8+1][sr]=a.y; xs[sc*8+2][sr]=a.z; xs[sc*8+3][sr]=a.w;
      xs[sc*8+4][sr]=b.x; xs[sc*8+5][sr]=b.y; xs[sc*8+6][sr]=b.z; xs[sc*8+7][sr]=b.w;
    }
    __syncthreads();
    for (int k = 0; k < 32; k++){
      float4 a4 = *(const float4*)&xs[k][tm];
      float4 b4 = *(const float4*)&ws[k][tn];
      float av[4] = {a4.x,a4.y,a4.z,a4.w};
      float bv[4] = {b4.x,b4.y,b4.z,b4.w};
      #pragma unroll
      for (int i=0;i<4;i++)
        #pragma unroll
        for (int j=0;j<4;j++)
          acc[i][j] += (double)av[i] * (double)bv[j];
    }
    __syncthreads();
  }
  #pragma unroll
  for (int i=0;i<4;i++){
    float4 o = make_float4((float)acc[i][0],(float)acc[i][1],(float)acc[i][2],(float)acc[i][3]);
    *(float4*)&logits[(size_t)(m0 + tm + i) * 64 + tn] = o;
  }
}

// ---------------- top-8 + softmax (wave per token) ----------------
__global__ __launch_bounds__(256) void k_topk(const float* __restrict__ logits,
                                              int* __restrict__ tk_idx,
                                              float* __restrict__ tk_w){
  const int lane = threadIdx.x & 63;
  const int t    = blockIdx.x * 4 + (threadIdx.x >> 6);
  float v = logits[(size_t)t * 64 + lane];
  const int myi = lane;
  float mv[8]; int mi[8];
  #pragma unroll
  for (int k = 0; k < 8; k++){
    float bv = v; int bi = myi;
    #pragma unroll
    for (int off = 32; off > 0; off >>= 1){
      float ov = __shfl_xor(bv, off, 64);
      int   oi = __shfl_xor(bi, off, 64);
      if (ov > bv || (ov == bv && oi < bi)){ bv = ov; bi = oi; }
    }
    mv[k] = bv; mi[k] = bi;
    if (bi == myi) v = -INFINITY;
  }
  float w[8]; float s = 0.f;
  #pragma unroll
  for (int k = 0; k < 8; k++){ w[k] = expf(mv[k] - mv[0]); s += w[k]; }
  float inv = 1.0f / s;
  if (lane == 0){
    #pragma unroll
    for (int k = 0; k < 8; k++){
      tk_idx[(size_t)t * 8 + k] = mi[k];
      tk_w [(size_t)t * 8 + k] = w[k] * inv;
    }
  }
}

// ---------------- per-chunk histogram ----------------
__global__ __launch_bounds__(256) void k_hist(const int* __restrict__ tk_idx,
                                              int* __restrict__ g_hist){
  __shared__ int h[4][64];
  const int tid = threadIdx.x, wave = tid >> 6;
  ((int*)h)[tid] = 0;
  __syncthreads();
  const int4* p = (const int4*)(tk_idx + blockIdx.x * 4096);
  #pragma unroll
  for (int i = 0; i < 4; i++){
    int4 v = p[i * 256 + tid];
    atomicAdd(&h[wave][v.x], 1); atomicAdd(&h[wave][v.y], 1);
    atomicAdd(&h[wave][v.z], 1); atomicAdd(&h[wave][v.w], 1);
  }
  __syncthreads();
  if (tid < 64)
    g_hist[blockIdx.x * 64 + tid] = h[0][tid] + h[1][tid] + h[2][tid] + h[3][tid];
}

// ---------------- scan: expert offsets + per-chunk bases ----------------
__global__ void k_scan(const int* __restrict__ g_hist,
                       int* __restrict__ offsets,
                       int* __restrict__ g_base){
  const int e = threadIdx.x;
  int h[CHUNKS]; int tot = 0;
  #pragma unroll
  for (int c = 0; c < CHUNKS; c++){ h[c] = g_hist[c * 64 + e]; tot += h[c]; }
  int inc = tot;
  #pragma unroll
  for (int off = 1; off < 64; off <<= 1){
    int n = __shfl_up(inc, off, 64);
    if (e >= off) inc += n;
  }
  int exc = inc - tot;
  offsets[e] = exc;
  if (e == 63) offsets[64] = inc;
  int b = exc;
  #pragma unroll
  for (int c = 0; c < CHUNKS; c++){ g_base[c * 64 + e] = b; b += h[c]; }
}

// ---------------- scatter: compact slots + inverse map ----------------
__global__ __launch_bounds__(256) void k_scatter(const int* __restrict__ tk_idx,
                                                 const int* __restrict__ g_base,
                                                 int* __restrict__ slot_token,
                                                 int* __restrict__ inv_pos){
  __shared__ int cnt[64];
  const int tid = threadIdx.x;
  if (tid < 64) cnt[tid] = g_base[blockIdx.x * 64 + tid];
  __syncthreads();
  const int base = blockIdx.x * 4096;
  #pragma unroll
  for (int i = 0; i < 16; i++){
    int gid = base + i * 256 + tid;
    int e = tk_idx[gid];
    int pos = atomicAdd(&cnt[e], 1);   // LDS atomic
    slot_token[pos] = gid >> 3;
    inv_pos[gid] = pos;
  }
}

// ---------------- GEMM1: h[slot][512] = silu(xb[tok] @ WupT[e]^T) ----------------
// Double-buffered LDS, prefetch-before-compute (T3-minimum 2-phase).
__global__ __launch_bounds__(256) void k_gemm1(const __bf16* __restrict__ xb,
                                               const __bf16* __restrict__ wupT,  // [E][H][D]
                                               const int* __restrict__ offsets,
                                               const int* __restrict__ slot_token,
                                               __bf16* __restrict__ h){
  const int e    = blockIdx.z;
  const int base = offsets[e];
  const int ne   = offsets[e + 1] - base;
  const int m0   = blockIdx.x * 128;
  if (m0 >= ne) return;
  const int n0   = blockIdx.y * 128;

  __shared__ __align__(16) __bf16 As[2][128 * 32];
  __shared__ __align__(16) __bf16 Bs[2][128 * 32];
  __shared__ int s_tok[128];

  const int tid = threadIdx.x;
  if (tid < 128){
    int r = m0 + tid;
    s_tok[tid] = slot_token[base + (r < ne ? r : 0)];
  }
  __syncthreads();

  const int wave = tid >> 6, lane = tid & 63;
  const int wm = (wave >> 1) << 6, wn = (wave & 1) << 6;
  const int sr = lane >> 2, sc = lane & 3;
  const int fr = lane & 15, fk = (lane >> 4) << 3;
  const __bf16* wB = wupT + (size_t)e * HDIM * DDIM + (size_t)n0 * DDIM;

  // hoisted staging source pointers (k0 added per iteration)
  const int rr0 = (wave << 5) + sr, rr1 = rr0 + 16;
  const __bf16* gA0 = xb + (size_t)s_tok[rr0] * DDIM + (sc << 3);
  const __bf16* gA1 = xb + (size_t)s_tok[rr1] * DDIM + (sc << 3);
  const __bf16* gB0 = wB + (size_t)rr0 * DDIM + (sc << 3);
  const __bf16* gB1 = wB + (size_t)rr1 * DDIM + (sc << 3);
  const int ld0 = (wave << 1) << 9, ld1 = ((wave << 1) + 1) << 9;

  f32x4 zero = {0.f, 0.f, 0.f, 0.f};
  f32x4 acc[4][4];
  #pragma unroll
  for (int i=0;i<4;i++)
    #pragma unroll
    for (int j=0;j<4;j++) acc[i][j] = zero;

  // prologue: stage tile 0 into buffer 0
  load_lds16(gA0, (void*)&As[0][ld0]);
  load_lds16(gA1, (void*)&As[0][ld1]);
  load_lds16(gB0, (void*)&Bs[0][ld0]);
  load_lds16(gB1, (void*)&Bs[0][ld1]);
  __syncthreads();   // vmcnt(0) drain + sync

  const int NK = DDIM / 32;
  for (int t = 0; t < NK; ++t){
    const int cur = t & 1;
    if (t + 1 < NK){
      const int k1 = (t + 1) << 5;
      const int nxt = cur ^ 1;
      load_lds16(gA0 + k1, (void*)&As[nxt][ld0]);
      load_lds16(gA1 + k1, (void*)&As[nxt][ld1]);
      load_lds16(gB0 + k1, (void*)&Bs[nxt][ld0]);
      load_lds16(gB1 + k1, (void*)&Bs[nxt][ld1]);
    }
    bf16x8 af[4], bg[4];
    #pragma unroll
    for (int i=0;i<4;i++) af[i] = *(const bf16x8*)&As[cur][((wm + (i<<4) + fr) << 5) + fk];
    #pragma unroll
    for (int j=0;j<4;j++) bg[j] = *(const bf16x8*)&Bs[cur][((wn + (j<<4) + fr) << 5) + fk];
    #pragma unroll
    for (int i=0;i<4;i++)
      #pragma unroll
      for (int j=0;j<4;j++)
        acc[i][j] = __builtin_amdgcn_mfma_f32_16x16x32_bf16(af[i], bg[j], acc[i][j], 0, 0, 0);
    __syncthreads();   // drains prefetch (vmcnt0) + protects cur for overwrite
  }

  const int cr = (lane >> 4) << 2, cc = lane & 15;
  #pragma unroll
  for (int i=0;i<4;i++){
    #pragma unroll
    for (int reg=0;reg<4;reg++){
      int rl = wm + (i << 4) + cr + reg;
      int gm = m0 + rl;
      if (gm < ne){
        __bf16* hrow = h + (size_t)(base + gm) * HDIM + n0 + wn;
        #pragma unroll
        for (int j=0;j<4;j++){
          float v  = acc[i][j][reg];
          float sv = v / (1.0f + __expf(-v));
          unsigned short u = f2bfbits(sv);
          int part = __shfl_xor((int)u, 1, 64);
          if (!(lane & 1)){
            unsigned int packed = ((unsigned int)(unsigned short)part << 16) | u;
            *(unsigned int*)((unsigned short*)hrow + (j << 4) + cc) = packed;
          }
        }
      }
    }
  }
}

// ---------------- GEMM2: y[slot][1024] = h[slot] @ WdownT[e]^T (bf16, unweighted) ----------------
__global__ __launch_bounds__(256) void k_gemm2(const __bf16* __restrict__ h,
                                               const __bf16* __restrict__ wdownT, // [E][D][H]
                                               const int* __restrict__ offsets,
                                               __bf16* __restrict__ y,
                                               int elo){
  const int e    = elo + blockIdx.z;
  const int base = offsets[e];
  const int ne   = offsets[e + 1] - base;
  const int m0   = blockIdx.x * 128;
  if (m0 >= ne) return;
  const int n0   = blockIdx.y * 128;
  const int ybase = offsets[elo];

  __shared__ __align__(16) __bf16 As[2][128 * 32];
  __shared__ __align__(16) __bf16 Bs[2][128 * 32];

  const int tid = threadIdx.x;
  const int wave = tid >> 6, lane = tid & 63;
  const int wm = (wave >> 1) << 6, wn = (wave & 1) << 6;
  const int sr = lane >> 2, sc = lane & 3;
  const int fr = lane & 15, fk = (lane >> 4) << 3;
  const __bf16* wB = wdownT + (size_t)e * DDIM * HDIM + (size_t)n0 * HDIM;

  const int rr0 = (wave << 5) + sr, rr1 = rr0 + 16;
  const int sl0 = (m0 + rr0 < ne) ? (m0 + rr0) : 0;
  const int sl1 = (m0 + rr1 < ne) ? (m0 + rr1) : 0;
  const __bf16* gA0 = h + (size_t)(base + sl0) * HDIM + (sc << 3);
  const __bf16* gA1 = h + (size_t)(base + sl1) * HDIM + (sc << 3);
  const __bf16* gB0 = wB + (size_t)rr0 * HDIM + (sc << 3);
  const __bf16* gB1 = wB + (size_t)rr1 * HDIM + (sc << 3);
  const int ld0 = (wave << 1) << 9, ld1 = ((wave << 1) + 1) << 9;

  f32x4 zero = {0.f, 0.f, 0.f, 0.f};
  f32x4 acc[4][4];
  #pragma unroll
  for (int i=0;i<4;i++)
    #pragma unroll
    for (int j=0;j<4;j++) acc[i][j] = zero;

  load_lds16(gA0, (void*)&As[0][ld0]);
  load_lds16(gA1, (void*)&As[0][ld1]);
  load_lds16(gB0, (void*)&Bs[0][ld0]);
  load_lds16(gB1, (void*)&Bs[0][ld1]);
  __syncthreads();

  const int NK = HDIM / 32;
  for (int t = 0; t < NK; ++t){
    const int cur = t & 1;
    if (t + 1 < NK){
      const int k1 = (t + 1) << 5;
      const int nxt = cur ^ 1;
      load_lds16(gA0 + k1, (void*)&As[nxt][ld0]);
      load_lds16(gA1 + k1, (void*)&As[nxt][ld1]);
      load_lds16(gB0 + k1, (void*)&Bs[nxt][ld0]);
      load_lds16(gB1 + k1, (void*)&Bs[nxt][ld1]);
    }
    bf16x8 af[4], bg[4];
    #pragma unroll
    for (int i=0;i<4;i++) af[i] = *(const bf16x8*)&As[cur][((wm + (i<<4) + fr) << 5) + fk];
    #pragma unroll
    for (int j=0;j<4;j++) bg[j] = *(const bf16x8*)&Bs[cur][((wn + (j<<4) + fr) << 5) + fk];
    #pragma unroll
    for (int i=0;i<4;i++)
      #pragma unroll
      for (int j=0;j<4;j++)
        acc[i][j] = __builtin_amdgcn_mfma_f32_16x16x32_bf16(af[i], bg[j], acc[i][j], 0, 0, 0);
    __syncthreads();
  }

  const int cr = (lane >> 4) << 2, cc = lane & 15;
  #pragma unroll
  for (int i=0;i<4;i++){
    #pragma unroll
    for (int reg=0;reg<4;reg++){
      int rl = wm + (i << 4) + cr + reg;
      int gm = m0 + rl;
      if (gm < ne){
        __bf16* yrow = y + (size_t)(base - ybase + gm) * DDIM + n0 + wn;
        #pragma unroll
        for (int j=0;j<4;j++){
          unsigned short u = f2bfbits(acc[i][j][reg]);
          int part = __shfl_xor((int)u, 1, 64);
          if (!(lane & 1)){
            unsigned int packed = ((unsigned int)(unsigned short)part << 16) | u;
            *(unsigned int*)((unsigned short*)yrow + (j << 4) + cc) = packed;
          }
        }
      }
    }
  }
}

// ---------------- combine: out[t] (+)= sum_k w_k * y[pos(t,k)] for experts in [elo,ehi) ----------------
__global__ __launch_bounds__(256) void k_combine(const __bf16* __restrict__ y,
                                                 const int* __restrict__ tk_idx,
                                                 const float* __restrict__ tk_w,
                                                 const int* __restrict__ inv_pos,
                                                 const int* __restrict__ offsets,
                                                 float* __restrict__ out,
                                                 int elo, int ehi, int first){
  const int t   = blockIdx.x;
  const int tid = threadIdx.x;
  __shared__ int se[8]; __shared__ float sw[8]; __shared__ int sp[8];
  if (tid < 8){
    se[tid] = tk_idx[(size_t)t * 8 + tid];
    sw[tid] = tk_w [(size_t)t * 8 + tid];
    sp[tid] = inv_pos[(size_t)t * 8 + tid];
  }
  __syncthreads();
  const int ybase = offsets[elo];
  const int c = tid << 2;
  float4 acc;
  if (first) acc = make_float4(0.f, 0.f, 0.f, 0.f);
  else       acc = *(const float4*)&out[(size_t)t * DDIM + c];
  #pragma unroll
  for (int k = 0; k < 8; k++){
    int e = se[k];
    if (e >= elo && e < ehi){
      const unsigned short* yr = (const unsigned short*)y + (size_t)(sp[k] - ybase) * DDIM + c;
      ushort4 raw = *(const ushort4*)yr;
      float w = sw[k];
      acc.x += w * bf2f(raw.x);
      acc.y += w * bf2f(raw.y);
      acc.z += w * bf2f(raw.z);
      acc.w += w * bf2f(raw.w);
    }
  }
  *(float4*)&out[(size_t)t * DDIM + c] = acc;
}

// ---------------- host launch ----------------
extern "C" void kernel_launch(void* const* d_in, const int* in_sizes, int n_in,
                              void* d_out, int out_size, void* d_ws, size_t ws_size,
                              hipStream_t stream){
  const float* x     = (const float*)d_in[0];
  const float* Wg    = (const float*)d_in[1];
  const float* Wup   = (const float*)d_in[2];
  const float* Wdown = (const float*)d_in[3];
  float* out = (float*)d_out;

  char* ws = (char*)d_ws;
  size_t off = 0;
  auto alloc = [&](size_t bytes) -> void* {
    void* p = ws + off;
    off += (bytes + 255) & ~(size_t)255;
    return p;
  };
  // Layout: [wupT][xb][logits] are DEAD after k_gemm1 and are reused as the
  // per-group y buffer (86 MB capacity ≈ 42k rows; a 32-expert group holds
  // ~32768±640 slots — huge margin).
  __bf16* wupT      = (__bf16*)alloc((size_t)NEXP * DDIM * HDIM * 2);  // 67.1 MB
  __bf16* xb        = (__bf16*)alloc((size_t)T_TOK * DDIM * 2);        // 16.8 MB
  float*  logits    = (float*)alloc((size_t)T_TOK * NEXP * 4);         //  2.1 MB
  __bf16* wdownT    = (__bf16*)alloc((size_t)NEXP * DDIM * HDIM * 2);  // 67.1 MB
  __bf16* hbuf      = (__bf16*)alloc((size_t)T_TOK * TOPK * HDIM * 2); // 67.1 MB
  int*    tk_idx    = (int*)  alloc((size_t)T_TOK * TOPK * 4);
  float*  tk_w      = (float*)alloc((size_t)T_TOK * TOPK * 4);
  int*    slot_tok  = (int*)  alloc((size_t)T_TOK * TOPK * 4);
  int*    inv_pos   = (int*)  alloc((size_t)T_TOK * TOPK * 4);
  int*    g_hist    = (int*)  alloc((size_t)CHUNKS * 64 * 4);
  int*    g_base    = (int*)  alloc((size_t)CHUNKS * 64 * 4);
  int*    offsets   = (int*)  alloc(512);
  __bf16* ybuf      = (__bf16*)ws;   // alias over wupT+xb+logits

  k_cvt_x<<<4096, 256, 0, stream>>>(x, xb);
  k_transpose_cvt<<<dim3(16, 32, 64), dim3(32, 8), 0, stream>>>(Wup,   wupT,   DDIM, HDIM);
  k_transpose_cvt<<<dim3(32, 16, 64), dim3(32, 8), 0, stream>>>(Wdown, wdownT, HDIM, DDIM);
  k_gate<<<T_TOK / 64, 256, 0, stream>>>(x, Wg, logits);
  k_topk<<<T_TOK / 4, 256, 0, stream>>>(logits, tk_idx, tk_w);
  k_hist<<<CHUNKS, 256, 0, stream>>>(tk_idx, g_hist);
  k_scan<<<1, 64, 0, stream>>>(g_hist, offsets, g_base);
  k_scatter<<<CHUNKS, 256, 0, stream>>>(tk_idx, g_base, slot_tok, inv_pos);
  k_gemm1<<<dim3(16, 4, 64), 256, 0, stream>>>(xb, wupT, offsets, slot_tok, hbuf);
  // group A: experts [0,32)
  k_gemm2<<<dim3(16, 8, 32), 256, 0, stream>>>(hbuf, wdownT, offsets, ybuf, 0);
  k_combine<<<T_TOK, 256, 0, stream>>>(ybuf, tk_idx, tk_w, inv_pos, offsets, out, 0, 32, 1);
  // group B: experts [32,64)
  k_gemm2<<<dim3(16, 8, 32), 256, 0, stream>>>(hbuf, wdownT, offsets, ybuf, 32);
  k_combine<<<T_TOK, 256, 0, stream>>>(ybuf, tk_idx, tk_w, inv_pos, offsets, out, 32, 64, 0);
}

// Round 5
// 733.115 us; speedup vs baseline: 1.0314x; 1.0314x over previous
//
#include <hip/hip_runtime.h>
#include <hip/hip_bf16.h>
#include <stdint.h>
#include <math.h>

#define T_TOK 8192
#define DDIM  1024
#define HDIM  512
#define NEXP  64
#define TOPK  8
#define CHUNKS 16

typedef __bf16 bf16x8 __attribute__((ext_vector_type(8)));
typedef float  f32x4  __attribute__((ext_vector_type(4)));

__device__ __forceinline__ void load_lds16(const void* gp, void* lp){
  __builtin_amdgcn_global_load_lds(
      (__attribute__((address_space(1))) void*)(uintptr_t)gp,
      (__attribute__((address_space(3))) void*)lp, 16, 0, 0);
}

__device__ __forceinline__ unsigned short f2bfbits(float f){
  union { __bf16 b; unsigned short u; } cv; cv.b = (__bf16)f; return cv.u;
}
__device__ __forceinline__ float bf2f(unsigned short s){
  unsigned int u = ((unsigned int)s) << 16; return __uint_as_float(u);
}

// ---------------- x -> bf16 ----------------
__global__ __launch_bounds__(256) void k_cvt_x(const float* __restrict__ x,
                                               __bf16* __restrict__ xb){
  size_t i   = (size_t)blockIdx.x * 256 + threadIdx.x;
  size_t off = i * 8;
  float4 v0 = *(const float4*)(x + off);
  float4 v1 = *(const float4*)(x + off + 4);
  bf16x8 o;
  o[0]=(__bf16)v0.x; o[1]=(__bf16)v0.y; o[2]=(__bf16)v0.z; o[3]=(__bf16)v0.w;
  o[4]=(__bf16)v1.x; o[5]=(__bf16)v1.y; o[6]=(__bf16)v1.z; o[7]=(__bf16)v1.w;
  *(bf16x8*)(xb + off) = o;
}

// ------- transpose + convert: src [z][R][C] f32 -> dst [z][C][R] bf16 -------
__global__ __launch_bounds__(256) void k_transpose_cvt(const float* __restrict__ src,
                                                       __bf16* __restrict__ dst,
                                                       int R, int C){
  __shared__ float tile[32][33];
  int z  = blockIdx.z;
  int c0 = blockIdx.x * 32;
  int r0 = blockIdx.y * 32;
  const float* s = src + (size_t)z * R * C;
  __bf16*      d = dst + (size_t)z * R * C;
  int tx = threadIdx.x, ty = threadIdx.y;
  #pragma unroll
  for (int i = ty; i < 32; i += 8)
    tile[i][tx] = s[(size_t)(r0 + i) * C + c0 + tx];
  __syncthreads();
  #pragma unroll
  for (int i = ty; i < 32; i += 8)
    d[(size_t)(c0 + i) * R + r0 + tx] = (__bf16)tile[tx][i];
}

// ---------------- gate GEMM: logits[T][64] (f64 accumulate) ----------------
__global__ __launch_bounds__(256) void k_gate(const float* __restrict__ x,
                                              const float* __restrict__ Wg,
                                              float* __restrict__ logits){
  __shared__ float xs[32][64];
  __shared__ float ws[32][64];
  const int tid = threadIdx.x;
  const int m0  = blockIdx.x * 64;
  const int tm  = (tid >> 4) << 2;
  const int tn  = (tid & 15) << 2;
  const int sr  = tid >> 2;
  const int sc  = tid & 3;
  double acc[4][4];
  #pragma unroll
  for (int i=0;i<4;i++)
    #pragma unroll
    for (int j=0;j<4;j++) acc[i][j]=0.0;

  for (int k0 = 0; k0 < DDIM; k0 += 32){
    {
      const float4* g = (const float4*)(Wg + (size_t)k0 * 64);
      float4* l = (float4*)&ws[0][0];
      l[tid]       = g[tid];
      l[tid + 256] = g[tid + 256];
    }
    {
      const float* g = x + (size_t)(m0 + sr) * DDIM + k0 + sc * 8;
      float4 a = *(const float4*)g;
      float4 b = *(const float4*)(g + 4);
      xs[sc*8+0][sr]=a.x; xs[sc*8+1][sr]=a.y; xs[sc*8+2][sr]=a.z; xs[sc*8+3][sr]=a.w;
      xs[sc*8+4][sr]=b.x; xs[sc*8+5][sr]=b.y; xs[sc*8+6][sr]=b.z; xs[sc*8+7][sr]=b.w;
    }
    __syncthreads();
    for (int k = 0; k < 32; k++){
      float4 a4 = *(const float4*)&xs[k][tm];
      float4 b4 = *(const float4*)&ws[k][tn];
      float av[4] = {a4.x,a4.y,a4.z,a4.w};
      float bv[4] = {b4.x,b4.y,b4.z,b4.w};
      #pragma unroll
      for (int i=0;i<4;i++)
        #pragma unroll
        for (int j=0;j<4;j++)
          acc[i][j] += (double)av[i] * (double)bv[j];
    }
    __syncthreads();
  }
  #pragma unroll
  for (int i=0;i<4;i++){
    float4 o = make_float4((float)acc[i][0],(float)acc[i][1],(float)acc[i][2],(float)acc[i][3]);
    *(float4*)&logits[(size_t)(m0 + tm + i) * 64 + tn] = o;
  }
}

// ---------------- top-8 + softmax (wave per token) ----------------
__global__ __launch_bounds__(256) void k_topk(const float* __restrict__ logits,
                                              int* __restrict__ tk_idx,
                                              float* __restrict__ tk_w){
  const int lane = threadIdx.x & 63;
  const int t    = blockIdx.x * 4 + (threadIdx.x >> 6);
  float v = logits[(size_t)t * 64 + lane];
  const int myi = lane;
  float mv[8]; int mi[8];
  #pragma unroll
  for (int k = 0; k < 8; k++){
    float bv = v; int bi = myi;
    #pragma unroll
    for (int off = 32; off > 0; off >>= 1){
      float ov = __shfl_xor(bv, off, 64);
      int   oi = __shfl_xor(bi, off, 64);
      if (ov > bv || (ov == bv && oi < bi)){ bv = ov; bi = oi; }
    }
    mv[k] = bv; mi[k] = bi;
    if (bi == myi) v = -INFINITY;
  }
  float w[8]; float s = 0.f;
  #pragma unroll
  for (int k = 0; k < 8; k++){ w[k] = expf(mv[k] - mv[0]); s += w[k]; }
  float inv = 1.0f / s;
  if (lane == 0){
    #pragma unroll
    for (int k = 0; k < 8; k++){
      tk_idx[(size_t)t * 8 + k] = mi[k];
      tk_w [(size_t)t * 8 + k] = w[k] * inv;
    }
  }
}

// ---------------- per-chunk histogram ----------------
__global__ __launch_bounds__(256) void k_hist(const int* __restrict__ tk_idx,
                                              int* __restrict__ g_hist){
  __shared__ int h[4][64];
  const int tid = threadIdx.x, wave = tid >> 6;
  ((int*)h)[tid] = 0;
  __syncthreads();
  const int4* p = (const int4*)(tk_idx + blockIdx.x * 4096);
  #pragma unroll
  for (int i = 0; i < 4; i++){
    int4 v = p[i * 256 + tid];
    atomicAdd(&h[wave][v.x], 1); atomicAdd(&h[wave][v.y], 1);
    atomicAdd(&h[wave][v.z], 1); atomicAdd(&h[wave][v.w], 1);
  }
  __syncthreads();
  if (tid < 64)
    g_hist[blockIdx.x * 64 + tid] = h[0][tid] + h[1][tid] + h[2][tid] + h[3][tid];
}

// ---------------- scan: expert offsets + per-chunk bases ----------------
__global__ void k_scan(const int* __restrict__ g_hist,
                       int* __restrict__ offsets,
                       int* __restrict__ g_base){
  const int e = threadIdx.x;
  int h[CHUNKS]; int tot = 0;
  #pragma unroll
  for (int c = 0; c < CHUNKS; c++){ h[c] = g_hist[c * 64 + e]; tot += h[c]; }
  int inc = tot;
  #pragma unroll
  for (int off = 1; off < 64; off <<= 1){
    int n = __shfl_up(inc, off, 64);
    if (e >= off) inc += n;
  }
  int exc = inc - tot;
  offsets[e] = exc;
  if (e == 63) offsets[64] = inc;
  int b = exc;
  #pragma unroll
  for (int c = 0; c < CHUNKS; c++){ g_base[c * 64 + e] = b; b += h[c]; }
}

// ---------------- scatter: compact slots + inverse map ----------------
__global__ __launch_bounds__(256) void k_scatter(const int* __restrict__ tk_idx,
                                                 const int* __restrict__ g_base,
                                                 int* __restrict__ slot_token,
                                                 int* __restrict__ inv_pos){
  __shared__ int cnt[64];
  const int tid = threadIdx.x;
  if (tid < 64) cnt[tid] = g_base[blockIdx.x * 64 + tid];
  __syncthreads();
  const int base = blockIdx.x * 4096;
  #pragma unroll
  for (int i = 0; i < 16; i++){
    int gid = base + i * 256 + tid;
    int e = tk_idx[gid];
    int pos = atomicAdd(&cnt[e], 1);   // LDS atomic
    slot_token[pos] = gid >> 3;
    inv_pos[gid] = pos;
  }
}

// ============ 256x256-tile grouped GEMM cores (BK=64, 8 waves, 2-phase dbuf) ============
// Wave grid 2(M)x4(N): wave tile 128x64. LDS 128KB (2 bufs x (A 32KB + B 32KB)).
// Staging: 4 rounds per matrix, linear global_load_lds (wave-uniform dest + lane*16).

// ---------------- GEMM1: h[slot][512] = silu(xb[tok] @ WupT[e]^T) ----------------
__global__ __launch_bounds__(512) void k_gemm1(const __bf16* __restrict__ xb,
                                               const __bf16* __restrict__ wupT,  // [E][H][D]
                                               const int* __restrict__ offsets,
                                               const int* __restrict__ slot_token,
                                               __bf16* __restrict__ h){
  const int e    = blockIdx.z;
  const int base = offsets[e];
  const int ne   = offsets[e + 1] - base;
  const int m0   = blockIdx.x * 256;
  if (m0 >= ne) return;
  const int n0   = blockIdx.y * 256;

  __shared__ __align__(16) __bf16 As[2][256 * 64];
  __shared__ __align__(16) __bf16 Bs[2][256 * 64];
  __shared__ int s_tok[256];

  const int tid = threadIdx.x;
  if (tid < 256){
    int r = m0 + tid;
    s_tok[tid] = slot_token[base + (r < ne ? r : (ne - 1))];
  }
  __syncthreads();

  const int wave = tid >> 6, lane = tid & 63;
  const int wm = (wave >> 2) << 7;   // 0 or 128
  const int wn = (wave & 3) << 6;    // 0,64,128,192
  const int fr = lane & 15, fk = (lane >> 4) << 3;
  const __bf16* wB = wupT + (size_t)e * HDIM * DDIM + (size_t)n0 * DDIM;

  // staging geometry: round q stages rows [q*64, q*64+64); this wave covers
  // rows q*64 + wave*8 .. +8, each row = 8 chunks of 16B, lane>>3=row, lane&7=chunk
  const int srow = (wave << 3) + (lane >> 3);
  const int scol = (lane & 7) << 3;
  const __bf16* gA[4]; const __bf16* gB[4]; int ldsOff[4];
  #pragma unroll
  for (int q = 0; q < 4; q++){
    int r = (q << 6) + srow;
    gA[q] = xb + (size_t)s_tok[r] * DDIM + scol;
    gB[q] = wB + (size_t)(r) * DDIM + scol;       // n0 row offset already in wB
    ldsOff[q] = (q << 12) + (wave << 9);          // q*4096 + wave*512 elements
  }

  f32x4 acc[8][4];
  #pragma unroll
  for (int i=0;i<8;i++)
    #pragma unroll
    for (int j=0;j<4;j++) acc[i][j] = (f32x4){0.f,0.f,0.f,0.f};

  // prologue
  #pragma unroll
  for (int q = 0; q < 4; q++){
    load_lds16(gA[q], (void*)&As[0][ldsOff[q]]);
    load_lds16(gB[q], (void*)&Bs[0][ldsOff[q]]);
  }
  __syncthreads();

  const int NK = DDIM / 64;
  for (int t = 0; t < NK; ++t){
    const int cur = t & 1;
    if (t + 1 < NK){
      const int k1 = (t + 1) << 6;
      const int nxt = cur ^ 1;
      #pragma unroll
      for (int q = 0; q < 4; q++){
        load_lds16(gA[q] + k1, (void*)&As[nxt][ldsOff[q]]);
        load_lds16(gB[q] + k1, (void*)&Bs[nxt][ldsOff[q]]);
      }
    }
    #pragma unroll
    for (int ks = 0; ks < 2; ks++){
      bf16x8 af[8], bg[4];
      #pragma unroll
      for (int i=0;i<8;i++) af[i] = *(const bf16x8*)&As[cur][((wm + (i<<4) + fr) << 6) + (ks<<5) + fk];
      #pragma unroll
      for (int j=0;j<4;j++) bg[j] = *(const bf16x8*)&Bs[cur][((wn + (j<<4) + fr) << 6) + (ks<<5) + fk];
      #pragma unroll
      for (int i=0;i<8;i++)
        #pragma unroll
        for (int j=0;j<4;j++)
          acc[i][j] = __builtin_amdgcn_mfma_f32_16x16x32_bf16(af[i], bg[j], acc[i][j], 0, 0, 0);
    }
    __syncthreads();
  }

  const int cr = (lane >> 4) << 2, cc = lane & 15;
  #pragma unroll
  for (int i=0;i<8;i++){
    #pragma unroll
    for (int reg=0;reg<4;reg++){
      int rl = wm + (i << 4) + cr + reg;
      int gm = m0 + rl;
      if (gm < ne){
        __bf16* hrow = h + (size_t)(base + gm) * HDIM + n0 + wn;
        #pragma unroll
        for (int j=0;j<4;j++){
          float v  = acc[i][j][reg];
          float sv = v / (1.0f + __expf(-v));
          unsigned short u = f2bfbits(sv);
          int part = __shfl_xor((int)u, 1, 64);
          if (!(lane & 1)){
            unsigned int packed = ((unsigned int)(unsigned short)part << 16) | u;
            *(unsigned int*)((unsigned short*)hrow + (j << 4) + cc) = packed;
          }
        }
      }
    }
  }
}

// ---------------- GEMM2: y[slot][1024] = h[slot] @ WdownT[e]^T (bf16, unweighted) ----------------
__global__ __launch_bounds__(512) void k_gemm2(const __bf16* __restrict__ h,
                                               const __bf16* __restrict__ wdownT, // [E][D][H]
                                               const int* __restrict__ offsets,
                                               __bf16* __restrict__ y,
                                               int elo){
  const int e    = elo + blockIdx.z;
  const int base = offsets[e];
  const int ne   = offsets[e + 1] - base;
  const int m0   = blockIdx.x * 256;
  if (m0 >= ne) return;
  const int n0   = blockIdx.y * 256;
  const int ybase = offsets[elo];

  __shared__ __align__(16) __bf16 As[2][256 * 64];
  __shared__ __align__(16) __bf16 Bs[2][256 * 64];

  const int tid = threadIdx.x;
  const int wave = tid >> 6, lane = tid & 63;
  const int wm = (wave >> 2) << 7;
  const int wn = (wave & 3) << 6;
  const int fr = lane & 15, fk = (lane >> 4) << 3;
  const __bf16* wB = wdownT + (size_t)e * DDIM * HDIM + (size_t)n0 * HDIM;

  const int srow = (wave << 3) + (lane >> 3);
  const int scol = (lane & 7) << 3;
  const __bf16* gA[4]; const __bf16* gB[4]; int ldsOff[4];
  #pragma unroll
  for (int q = 0; q < 4; q++){
    int r = (q << 6) + srow;
    int sl = m0 + r; if (sl >= ne) sl = ne - 1;
    gA[q] = h + (size_t)(base + sl) * HDIM + scol;
    gB[q] = wB + (size_t)r * HDIM + scol;
    ldsOff[q] = (q << 12) + (wave << 9);
  }

  f32x4 acc[8][4];
  #pragma unroll
  for (int i=0;i<8;i++)
    #pragma unroll
    for (int j=0;j<4;j++) acc[i][j] = (f32x4){0.f,0.f,0.f,0.f};

  #pragma unroll
  for (int q = 0; q < 4; q++){
    load_lds16(gA[q], (void*)&As[0][ldsOff[q]]);
    load_lds16(gB[q], (void*)&Bs[0][ldsOff[q]]);
  }
  __syncthreads();

  const int NK = HDIM / 64;
  for (int t = 0; t < NK; ++t){
    const int cur = t & 1;
    if (t + 1 < NK){
      const int k1 = (t + 1) << 6;
      const int nxt = cur ^ 1;
      #pragma unroll
      for (int q = 0; q < 4; q++){
        load_lds16(gA[q] + k1, (void*)&As[nxt][ldsOff[q]]);
        load_lds16(gB[q] + k1, (void*)&Bs[nxt][ldsOff[q]]);
      }
    }
    #pragma unroll
    for (int ks = 0; ks < 2; ks++){
      bf16x8 af[8], bg[4];
      #pragma unroll
      for (int i=0;i<8;i++) af[i] = *(const bf16x8*)&As[cur][((wm + (i<<4) + fr) << 6) + (ks<<5) + fk];
      #pragma unroll
      for (int j=0;j<4;j++) bg[j] = *(const bf16x8*)&Bs[cur][((wn + (j<<4) + fr) << 6) + (ks<<5) + fk];
      #pragma unroll
      for (int i=0;i<8;i++)
        #pragma unroll
        for (int j=0;j<4;j++)
          acc[i][j] = __builtin_amdgcn_mfma_f32_16x16x32_bf16(af[i], bg[j], acc[i][j], 0, 0, 0);
    }
    __syncthreads();
  }

  const int cr = (lane >> 4) << 2, cc = lane & 15;
  #pragma unroll
  for (int i=0;i<8;i++){
    #pragma unroll
    for (int reg=0;reg<4;reg++){
      int rl = wm + (i << 4) + cr + reg;
      int gm = m0 + rl;
      if (gm < ne){
        __bf16* yrow = y + (size_t)(base - ybase + gm) * DDIM + n0 + wn;
        #pragma unroll
        for (int j=0;j<4;j++){
          unsigned short u = f2bfbits(acc[i][j][reg]);
          int part = __shfl_xor((int)u, 1, 64);
          if (!(lane & 1)){
            unsigned int packed = ((unsigned int)(unsigned short)part << 16) | u;
            *(unsigned int*)((unsigned short*)yrow + (j << 4) + cc) = packed;
          }
        }
      }
    }
  }
}

// ---------------- combine: out[t] (+)= sum_k w_k * y[pos(t,k)] for experts in [elo,ehi) ----------------
__global__ __launch_bounds__(256) void k_combine(const __bf16* __restrict__ y,
                                                 const int* __restrict__ tk_idx,
                                                 const float* __restrict__ tk_w,
                                                 const int* __restrict__ inv_pos,
                                                 const int* __restrict__ offsets,
                                                 float* __restrict__ out,
                                                 int elo, int ehi, int first){
  const int t   = blockIdx.x;
  const int tid = threadIdx.x;
  __shared__ int se[8]; __shared__ float sw[8]; __shared__ int sp[8];
  if (tid < 8){
    se[tid] = tk_idx[(size_t)t * 8 + tid];
    sw[tid] = tk_w [(size_t)t * 8 + tid];
    sp[tid] = inv_pos[(size_t)t * 8 + tid];
  }
  __syncthreads();
  const int ybase = offsets[elo];
  const int c = tid << 2;
  float4 acc;
  if (first) acc = make_float4(0.f, 0.f, 0.f, 0.f);
  else       acc = *(const float4*)&out[(size_t)t * DDIM + c];
  #pragma unroll
  for (int k = 0; k < 8; k++){
    int e = se[k];
    if (e >= elo && e < ehi){
      const unsigned short* yr = (const unsigned short*)y + (size_t)(sp[k] - ybase) * DDIM + c;
      ushort4 raw = *(const ushort4*)yr;
      float w = sw[k];
      acc.x += w * bf2f(raw.x);
      acc.y += w * bf2f(raw.y);
      acc.z += w * bf2f(raw.z);
      acc.w += w * bf2f(raw.w);
    }
  }
  *(float4*)&out[(size_t)t * DDIM + c] = acc;
}

// ---------------- host launch ----------------
extern "C" void kernel_launch(void* const* d_in, const int* in_sizes, int n_in,
                              void* d_out, int out_size, void* d_ws, size_t ws_size,
                              hipStream_t stream){
  const float* x     = (const float*)d_in[0];
  const float* Wg    = (const float*)d_in[1];
  const float* Wup   = (const float*)d_in[2];
  const float* Wdown = (const float*)d_in[3];
  float* out = (float*)d_out;

  char* ws = (char*)d_ws;
  size_t off = 0;
  auto alloc = [&](size_t bytes) -> void* {
    void* p = ws + off;
    off += (bytes + 255) & ~(size_t)255;
    return p;
  };
  // Layout: [wupT][xb][logits] are DEAD after k_gemm1 and are reused as the
  // per-group y buffer (86 MB capacity ≈ 42k rows; a 32-expert group holds
  // ~32768±640 slots — huge margin).
  __bf16* wupT      = (__bf16*)alloc((size_t)NEXP * DDIM * HDIM * 2);  // 67.1 MB
  __bf16* xb        = (__bf16*)alloc((size_t)T_TOK * DDIM * 2);        // 16.8 MB
  float*  logits    = (float*)alloc((size_t)T_TOK * NEXP * 4);         //  2.1 MB
  __bf16* wdownT    = (__bf16*)alloc((size_t)NEXP * DDIM * HDIM * 2);  // 67.1 MB
  __bf16* hbuf      = (__bf16*)alloc((size_t)T_TOK * TOPK * HDIM * 2); // 67.1 MB
  int*    tk_idx    = (int*)  alloc((size_t)T_TOK * TOPK * 4);
  float*  tk_w      = (float*)alloc((size_t)T_TOK * TOPK * 4);
  int*    slot_tok  = (int*)  alloc((size_t)T_TOK * TOPK * 4);
  int*    inv_pos   = (int*)  alloc((size_t)T_TOK * TOPK * 4);
  int*    g_hist    = (int*)  alloc((size_t)CHUNKS * 64 * 4);
  int*    g_base    = (int*)  alloc((size_t)CHUNKS * 64 * 4);
  int*    offsets   = (int*)  alloc(512);
  __bf16* ybuf      = (__bf16*)ws;   // alias over wupT+xb+logits

  k_cvt_x<<<4096, 256, 0, stream>>>(x, xb);
  k_transpose_cvt<<<dim3(16, 32, 64), dim3(32, 8), 0, stream>>>(Wup,   wupT,   DDIM, HDIM);
  k_transpose_cvt<<<dim3(32, 16, 64), dim3(32, 8), 0, stream>>>(Wdown, wdownT, HDIM, DDIM);
  k_gate<<<T_TOK / 64, 256, 0, stream>>>(x, Wg, logits);
  k_topk<<<T_TOK / 4, 256, 0, stream>>>(logits, tk_idx, tk_w);
  k_hist<<<CHUNKS, 256, 0, stream>>>(tk_idx, g_hist);
  k_scan<<<1, 64, 0, stream>>>(g_hist, offsets, g_base);
  k_scatter<<<CHUNKS, 256, 0, stream>>>(tk_idx, g_base, slot_tok, inv_pos);
  // 256x256-tile grouped GEMMs (8 waves/block)
  k_gemm1<<<dim3(8, 2, 64), 512, 0, stream>>>(xb, wupT, offsets, slot_tok, hbuf);
  // group A: experts [0,32)
  k_gemm2<<<dim3(8, 4, 32), 512, 0, stream>>>(hbuf, wdownT, offsets, ybuf, 0);
  k_combine<<<T_TOK, 256, 0, stream>>>(ybuf, tk_idx, tk_w, inv_pos, offsets, out, 0, 32, 1);
  // group B: experts [32,64)
  k_gemm2<<<dim3(8, 4, 32), 512, 0, stream>>>(hbuf, wdownT, offsets, ybuf, 32);
  k_combine<<<T_TOK, 256, 0, stream>>>(ybuf, tk_idx, tk_w, inv_pos, offsets, out, 32, 64, 0);
}

// Round 7
// 676.243 us; speedup vs baseline: 1.1181x; 1.0841x over previous
//
#include <hip/hip_runtime.h>
#include <hip/hip_bf16.h>
#include <stdint.h>
#include <math.h>

#define T_TOK 8192
#define DDIM  1024
#define HDIM  512
#define NEXP  64
#define TOPK  8
#define CHUNKS 16

typedef __bf16 bf16x8 __attribute__((ext_vector_type(8)));
typedef float  f32x4  __attribute__((ext_vector_type(4)));

__device__ __forceinline__ void load_lds16(const void* gp, void* lp){
  __builtin_amdgcn_global_load_lds(
      (__attribute__((address_space(1))) void*)(uintptr_t)gp,
      (__attribute__((address_space(3))) void*)lp, 16, 0, 0);
}

__device__ __forceinline__ unsigned short f2bfbits(float f){
  union { __bf16 b; unsigned short u; } cv; cv.b = (__bf16)f; return cv.u;
}
__device__ __forceinline__ float bf2f(unsigned short s){
  unsigned int u = ((unsigned int)s) << 16; return __uint_as_float(u);
}

// ---------------- x -> bf16 ----------------
__global__ __launch_bounds__(256) void k_cvt_x(const float* __restrict__ x,
                                               __bf16* __restrict__ xb){
  size_t i   = (size_t)blockIdx.x * 256 + threadIdx.x;
  size_t off = i * 8;
  float4 v0 = *(const float4*)(x + off);
  float4 v1 = *(const float4*)(x + off + 4);
  bf16x8 o;
  o[0]=(__bf16)v0.x; o[1]=(__bf16)v0.y; o[2]=(__bf16)v0.z; o[3]=(__bf16)v0.w;
  o[4]=(__bf16)v1.x; o[5]=(__bf16)v1.y; o[6]=(__bf16)v1.z; o[7]=(__bf16)v1.w;
  *(bf16x8*)(xb + off) = o;
}

// ------- transpose + convert: src [z][R][C] f32 -> dst [z][C][R] bf16 -------
__global__ __launch_bounds__(256) void k_transpose_cvt(const float* __restrict__ src,
                                                       __bf16* __restrict__ dst,
                                                       int R, int C){
  __shared__ float tile[32][33];
  int z  = blockIdx.z;
  int c0 = blockIdx.x * 32;
  int r0 = blockIdx.y * 32;
  const float* s = src + (size_t)z * R * C;
  __bf16*      d = dst + (size_t)z * R * C;
  int tx = threadIdx.x, ty = threadIdx.y;
  #pragma unroll
  for (int i = ty; i < 32; i += 8)
    tile[i][tx] = s[(size_t)(r0 + i) * C + c0 + tx];
  __syncthreads();
  #pragma unroll
  for (int i = ty; i < 32; i += 8)
    d[(size_t)(c0 + i) * R + r0 + tx] = (__bf16)tile[tx][i];
}

// ---------------- gate GEMM: logits[T][64] (f64 accumulate) ----------------
__global__ __launch_bounds__(256) void k_gate(const float* __restrict__ x,
                                              const float* __restrict__ Wg,
                                              float* __restrict__ logits){
  __shared__ float xs[32][64];
  __shared__ float ws[32][64];
  const int tid = threadIdx.x;
  const int m0  = blockIdx.x * 64;
  const int tm  = (tid >> 4) << 2;
  const int tn  = (tid & 15) << 2;
  const int sr  = tid >> 2;
  const int sc  = tid & 3;
  double acc[4][4];
  #pragma unroll
  for (int i=0;i<4;i++)
    #pragma unroll
    for (int j=0;j<4;j++) acc[i][j]=0.0;

  for (int k0 = 0; k0 < DDIM; k0 += 32){
    {
      const float4* g = (const float4*)(Wg + (size_t)k0 * 64);
      float4* l = (float4*)&ws[0][0];
      l[tid]       = g[tid];
      l[tid + 256] = g[tid + 256];
    }
    {
      const float* g = x + (size_t)(m0 + sr) * DDIM + k0 + sc * 8;
      float4 a = *(const float4*)g;
      float4 b = *(const float4*)(g + 4);
      xs[sc*8+0][sr]=a.x; xs[sc*8+1][sr]=a.y; xs[sc*8+2][sr]=a.z; xs[sc*8+3][sr]=a.w;
      xs[sc*8+4][sr]=b.x; xs[sc*8+5][sr]=b.y; xs[sc*8+6][sr]=b.z; xs[sc*8+7][sr]=b.w;
    }
    __syncthreads();
    for (int k = 0; k < 32; k++){
      float4 a4 = *(const float4*)&xs[k][tm];
      float4 b4 = *(const float4*)&ws[k][tn];
      float av[4] = {a4.x,a4.y,a4.z,a4.w};
      float bv[4] = {b4.x,b4.y,b4.z,b4.w};
      #pragma unroll
      for (int i=0;i<4;i++)
        #pragma unroll
        for (int j=0;j<4;j++)
          acc[i][j] += (double)av[i] * (double)bv[j];
    }
    __syncthreads();
  }
  #pragma unroll
  for (int i=0;i<4;i++){
    float4 o = make_float4((float)acc[i][0],(float)acc[i][1],(float)acc[i][2],(float)acc[i][3]);
    *(float4*)&logits[(size_t)(m0 + tm + i) * 64 + tn] = o;
  }
}

// ---------------- top-8 + softmax (wave per token) ----------------
__global__ __launch_bounds__(256) void k_topk(const float* __restrict__ logits,
                                              int* __restrict__ tk_idx,
                                              float* __restrict__ tk_w){
  const int lane = threadIdx.x & 63;
  const int t    = blockIdx.x * 4 + (threadIdx.x >> 6);
  float v = logits[(size_t)t * 64 + lane];
  const int myi = lane;
  float mv[8]; int mi[8];
  #pragma unroll
  for (int k = 0; k < 8; k++){
    float bv = v; int bi = myi;
    #pragma unroll
    for (int off = 32; off > 0; off >>= 1){
      float ov = __shfl_xor(bv, off, 64);
      int   oi = __shfl_xor(bi, off, 64);
      if (ov > bv || (ov == bv && oi < bi)){ bv = ov; bi = oi; }
    }
    mv[k] = bv; mi[k] = bi;
    if (bi == myi) v = -INFINITY;
  }
  float w[8]; float s = 0.f;
  #pragma unroll
  for (int k = 0; k < 8; k++){ w[k] = expf(mv[k] - mv[0]); s += w[k]; }
  float inv = 1.0f / s;
  if (lane == 0){
    #pragma unroll
    for (int k = 0; k < 8; k++){
      tk_idx[(size_t)t * 8 + k] = mi[k];
      tk_w [(size_t)t * 8 + k] = w[k] * inv;
    }
  }
}

// ---------------- per-chunk histogram ----------------
__global__ __launch_bounds__(256) void k_hist(const int* __restrict__ tk_idx,
                                              int* __restrict__ g_hist){
  __shared__ int h[4][64];
  const int tid = threadIdx.x, wave = tid >> 6;
  ((int*)h)[tid] = 0;
  __syncthreads();
  const int4* p = (const int4*)(tk_idx + blockIdx.x * 4096);
  #pragma unroll
  for (int i = 0; i < 4; i++){
    int4 v = p[i * 256 + tid];
    atomicAdd(&h[wave][v.x], 1); atomicAdd(&h[wave][v.y], 1);
    atomicAdd(&h[wave][v.z], 1); atomicAdd(&h[wave][v.w], 1);
  }
  __syncthreads();
  if (tid < 64)
    g_hist[blockIdx.x * 64 + tid] = h[0][tid] + h[1][tid] + h[2][tid] + h[3][tid];
}

// ---------------- scan: expert offsets + per-chunk bases ----------------
__global__ void k_scan(const int* __restrict__ g_hist,
                       int* __restrict__ offsets,
                       int* __restrict__ g_base){
  const int e = threadIdx.x;
  int h[CHUNKS]; int tot = 0;
  #pragma unroll
  for (int c = 0; c < CHUNKS; c++){ h[c] = g_hist[c * 64 + e]; tot += h[c]; }
  int inc = tot;
  #pragma unroll
  for (int off = 1; off < 64; off <<= 1){
    int n = __shfl_up(inc, off, 64);
    if (e >= off) inc += n;
  }
  int exc = inc - tot;
  offsets[e] = exc;
  if (e == 63) offsets[64] = inc;
  int b = exc;
  #pragma unroll
  for (int c = 0; c < CHUNKS; c++){ g_base[c * 64 + e] = b; b += h[c]; }
}

// ---------------- scatter: compact slots + inverse map ----------------
__global__ __launch_bounds__(256) void k_scatter(const int* __restrict__ tk_idx,
                                                 const int* __restrict__ g_base,
                                                 int* __restrict__ slot_token,
                                                 int* __restrict__ inv_pos){
  __shared__ int cnt[64];
  const int tid = threadIdx.x;
  if (tid < 64) cnt[tid] = g_base[blockIdx.x * 64 + tid];
  __syncthreads();
  const int base = blockIdx.x * 4096;
  #pragma unroll
  for (int i = 0; i < 16; i++){
    int gid = base + i * 256 + tid;
    int e = tk_idx[gid];
    int pos = atomicAdd(&cnt[e], 1);   // LDS atomic
    slot_token[pos] = gid >> 3;
    inv_pos[gid] = pos;
  }
}

// ============ 256x256-tile grouped GEMM cores (BK=64, 8 waves, 2-phase dbuf) ============
// LDS tiles [256][64] bf16, XOR-swizzled: slot (row, chunk) holds global 16B-chunk
// (chunk ^ (row&7)). gload_lds keeps a LINEAR dest; the per-lane GLOBAL source is
// inverse-permuted; ds_reads apply the same XOR (T2, rule-21 both-sides pattern).

// ---------------- GEMM1: h[slot][512] = silu(xb[tok] @ WupT[e]^T) ----------------
__global__ __launch_bounds__(512) void k_gemm1(const __bf16* __restrict__ xb,
                                               const __bf16* __restrict__ wupT,  // [E][H][D]
                                               const int* __restrict__ offsets,
                                               const int* __restrict__ slot_token,
                                               __bf16* __restrict__ h){
  const int e    = blockIdx.z;
  const int base = offsets[e];
  const int ne   = offsets[e + 1] - base;
  const int m0   = blockIdx.x * 256;
  if (m0 >= ne) return;
  const int n0   = blockIdx.y * 256;

  __shared__ __align__(16) __bf16 As[2][256 * 64];
  __shared__ __align__(16) __bf16 Bs[2][256 * 64];
  __shared__ int s_tok[256];

  const int tid = threadIdx.x;
  if (tid < 256){
    int r = m0 + tid;
    s_tok[tid] = slot_token[base + (r < ne ? r : (ne - 1))];
  }
  __syncthreads();

  const int wave = tid >> 6, lane = tid & 63;
  const int wm = (wave >> 2) << 7;   // 0 or 128
  const int wn = (wave & 3) << 6;    // 0,64,128,192
  const int fr = lane & 15, kc = lane >> 4;
  const int rxor = fr & 7;
  const __bf16* wB = wupT + (size_t)e * HDIM * DDIM + (size_t)n0 * DDIM;

  // staging: lane covers (row = lane>>3 within wave-stripe, chunk = lane&7);
  // inverse-swizzled source chunk = (lane&7) ^ (row&7) = (lane&7) ^ (lane>>3)
  const int srow = (wave << 3) + (lane >> 3);
  const int scol = (((lane & 7) ^ (lane >> 3)) << 3);
  const __bf16* gA[4]; const __bf16* gB[4]; int ldsOff[4];
  #pragma unroll
  for (int q = 0; q < 4; q++){
    int r = (q << 6) + srow;
    gA[q] = xb + (size_t)s_tok[r] * DDIM + scol;
    gB[q] = wB + (size_t)r * DDIM + scol;
    ldsOff[q] = (q << 12) + (wave << 9);          // linear dest
  }

  f32x4 acc[8][4];
  #pragma unroll
  for (int i=0;i<8;i++)
    #pragma unroll
    for (int j=0;j<4;j++) acc[i][j] = (f32x4){0.f,0.f,0.f,0.f};

  // prologue
  #pragma unroll
  for (int q = 0; q < 4; q++){
    load_lds16(gA[q], (void*)&As[0][ldsOff[q]]);
    load_lds16(gB[q], (void*)&Bs[0][ldsOff[q]]);
  }
  __syncthreads();

  const int NK = DDIM / 64;
  for (int t = 0; t < NK; ++t){
    const int cur = t & 1;
    if (t + 1 < NK){
      const int k1 = (t + 1) << 6;
      const int nxt = cur ^ 1;
      #pragma unroll
      for (int q = 0; q < 4; q++){
        load_lds16(gA[q] + k1, (void*)&As[nxt][ldsOff[q]]);
        load_lds16(gB[q] + k1, (void*)&Bs[nxt][ldsOff[q]]);
      }
    }
    #pragma unroll
    for (int ks = 0; ks < 2; ks++){
      const int cA = (((ks << 2) + kc) ^ rxor) << 3;   // swizzled chunk (elements)
      bf16x8 af[8], bg[4];
      #pragma unroll
      for (int i=0;i<8;i++) af[i] = *(const bf16x8*)&As[cur][((wm + (i<<4) + fr) << 6) + cA];
      #pragma unroll
      for (int j=0;j<4;j++) bg[j] = *(const bf16x8*)&Bs[cur][((wn + (j<<4) + fr) << 6) + cA];
      #pragma unroll
      for (int i=0;i<8;i++)
        #pragma unroll
        for (int j=0;j<4;j++)
          acc[i][j] = __builtin_amdgcn_mfma_f32_16x16x32_bf16(af[i], bg[j], acc[i][j], 0, 0, 0);
    }
    __syncthreads();
  }

  const int cr = (lane >> 4) << 2, cc = lane & 15;
  #pragma unroll
  for (int i=0;i<8;i++){
    #pragma unroll
    for (int reg=0;reg<4;reg++){
      int rl = wm + (i << 4) + cr + reg;
      int gm = m0 + rl;
      if (gm < ne){
        __bf16* hrow = h + (size_t)(base + gm) * HDIM + n0 + wn;
        #pragma unroll
        for (int j=0;j<4;j++){
          float v  = acc[i][j][reg];
          float sv = v / (1.0f + __expf(-v));
          unsigned short u = f2bfbits(sv);
          int part = __shfl_xor((int)u, 1, 64);
          if (!(lane & 1)){
            unsigned int packed = ((unsigned int)(unsigned short)part << 16) | u;
            *(unsigned int*)((unsigned short*)hrow + (j << 4) + cc) = packed;
          }
        }
      }
    }
  }
}

// ---------------- GEMM2: y[slot][1024] = h[slot] @ WdownT[e]^T (bf16, unweighted) ----------------
__global__ __launch_bounds__(512) void k_gemm2(const __bf16* __restrict__ h,
                                               const __bf16* __restrict__ wdownT, // [E][D][H]
                                               const int* __restrict__ offsets,
                                               __bf16* __restrict__ y,
                                               int elo){
  const int e    = elo + blockIdx.z;
  const int base = offsets[e];
  const int ne   = offsets[e + 1] - base;
  const int m0   = blockIdx.x * 256;
  if (m0 >= ne) return;
  const int n0   = blockIdx.y * 256;
  const int ybase = offsets[elo];

  __shared__ __align__(16) __bf16 As[2][256 * 64];
  __shared__ __align__(16) __bf16 Bs[2][256 * 64];

  const int tid = threadIdx.x;
  const int wave = tid >> 6, lane = tid & 63;
  const int wm = (wave >> 2) << 7;
  const int wn = (wave & 3) << 6;
  const int fr = lane & 15, kc = lane >> 4;
  const int rxor = fr & 7;
  const __bf16* wB = wdownT + (size_t)e * DDIM * HDIM + (size_t)n0 * HDIM;

  const int srow = (wave << 3) + (lane >> 3);
  const int scol = (((lane & 7) ^ (lane >> 3)) << 3);
  const __bf16* gA[4]; const __bf16* gB[4]; int ldsOff[4];
  #pragma unroll
  for (int q = 0; q < 4; q++){
    int r = (q << 6) + srow;
    int sl = m0 + r; if (sl >= ne) sl = ne - 1;
    gA[q] = h + (size_t)(base + sl) * HDIM + scol;
    gB[q] = wB + (size_t)r * HDIM + scol;
    ldsOff[q] = (q << 12) + (wave << 9);
  }

  f32x4 acc[8][4];
  #pragma unroll
  for (int i=0;i<8;i++)
    #pragma unroll
    for (int j=0;j<4;j++) acc[i][j] = (f32x4){0.f,0.f,0.f,0.f};

  #pragma unroll
  for (int q = 0; q < 4; q++){
    load_lds16(gA[q], (void*)&As[0][ldsOff[q]]);
    load_lds16(gB[q], (void*)&Bs[0][ldsOff[q]]);
  }
  __syncthreads();

  const int NK = HDIM / 64;
  for (int t = 0; t < NK; ++t){
    const int cur = t & 1;
    if (t + 1 < NK){
      const int k1 = (t + 1) << 6;
      const int nxt = cur ^ 1;
      #pragma unroll
      for (int q = 0; q < 4; q++){
        load_lds16(gA[q] + k1, (void*)&As[nxt][ldsOff[q]]);
        load_lds16(gB[q] + k1, (void*)&Bs[nxt][ldsOff[q]]);
      }
    }
    #pragma unroll
    for (int ks = 0; ks < 2; ks++){
      const int cA = (((ks << 2) + kc) ^ rxor) << 3;
      bf16x8 af[8], bg[4];
      #pragma unroll
      for (int i=0;i<8;i++) af[i] = *(const bf16x8*)&As[cur][((wm + (i<<4) + fr) << 6) + cA];
      #pragma unroll
      for (int j=0;j<4;j++) bg[j] = *(const bf16x8*)&Bs[cur][((wn + (j<<4) + fr) << 6) + cA];
      #pragma unroll
      for (int i=0;i<8;i++)
        #pragma unroll
        for (int j=0;j<4;j++)
          acc[i][j] = __builtin_amdgcn_mfma_f32_16x16x32_bf16(af[i], bg[j], acc[i][j], 0, 0, 0);
    }
    __syncthreads();
  }

  const int cr = (lane >> 4) << 2, cc = lane & 15;
  #pragma unroll
  for (int i=0;i<8;i++){
    #pragma unroll
    for (int reg=0;reg<4;reg++){
      int rl = wm + (i << 4) + cr + reg;
      int gm = m0 + rl;
      if (gm < ne){
        __bf16* yrow = y + (size_t)(base - ybase + gm) * DDIM + n0 + wn;
        #pragma unroll
        for (int j=0;j<4;j++){
          unsigned short u = f2bfbits(acc[i][j][reg]);
          int part = __shfl_xor((int)u, 1, 64);
          if (!(lane & 1)){
            unsigned int packed = ((unsigned int)(unsigned short)part << 16) | u;
            *(unsigned int*)((unsigned short*)yrow + (j << 4) + cc) = packed;
          }
        }
      }
    }
  }
}

// ---------------- combine: out[t] (+)= sum_k w_k * y[pos(t,k)] for experts in [elo,ehi) ----------------
__global__ __launch_bounds__(256) void k_combine(const __bf16* __restrict__ y,
                                                 const int* __restrict__ tk_idx,
                                                 const float* __restrict__ tk_w,
                                                 const int* __restrict__ inv_pos,
                                                 const int* __restrict__ offsets,
                                                 float* __restrict__ out,
                                                 int elo, int ehi, int first){
  const int t   = blockIdx.x;
  const int tid = threadIdx.x;
  __shared__ int se[8]; __shared__ float sw[8]; __shared__ int sp[8];
  if (tid < 8){
    se[tid] = tk_idx[(size_t)t * 8 + tid];
    sw[tid] = tk_w [(size_t)t * 8 + tid];
    sp[tid] = inv_pos[(size_t)t * 8 + tid];
  }
  __syncthreads();
  const int ybase = offsets[elo];
  const int c = tid << 2;
  float4 acc;
  if (first) acc = make_float4(0.f, 0.f, 0.f, 0.f);
  else       acc = *(const float4*)&out[(size_t)t * DDIM + c];
  #pragma unroll
  for (int k = 0; k < 8; k++){
    int e = se[k];
    if (e >= elo && e < ehi){
      const unsigned short* yr = (const unsigned short*)y + (size_t)(sp[k] - ybase) * DDIM + c;
      ushort4 raw = *(const ushort4*)yr;
      float w = sw[k];
      acc.x += w * bf2f(raw.x);
      acc.y += w * bf2f(raw.y);
      acc.z += w * bf2f(raw.z);
      acc.w += w * bf2f(raw.w);
    }
  }
  *(float4*)&out[(size_t)t * DDIM + c] = acc;
}

// ---------------- host launch ----------------
extern "C" void kernel_launch(void* const* d_in, const int* in_sizes, int n_in,
                              void* d_out, int out_size, void* d_ws, size_t ws_size,
                              hipStream_t stream){
  const float* x     = (const float*)d_in[0];
  const float* Wg    = (const float*)d_in[1];
  const float* Wup   = (const float*)d_in[2];
  const float* Wdown = (const float*)d_in[3];
  float* out = (float*)d_out;

  char* ws = (char*)d_ws;
  size_t off = 0;
  auto alloc = [&](size_t bytes) -> void* {
    void* p = ws + off;
    off += (bytes + 255) & ~(size_t)255;
    return p;
  };
  // Layout: [wupT][xb][logits] are DEAD after k_gemm1 and are reused as the
  // per-group y buffer (86 MB capacity ≈ 42k rows; a 32-expert group holds
  // ~32768±640 slots — huge margin).
  __bf16* wupT      = (__bf16*)alloc((size_t)NEXP * DDIM * HDIM * 2);  // 67.1 MB
  __bf16* xb        = (__bf16*)alloc((size_t)T_TOK * DDIM * 2);        // 16.8 MB
  float*  logits    = (float*)alloc((size_t)T_TOK * NEXP * 4);         //  2.1 MB
  __bf16* wdownT    = (__bf16*)alloc((size_t)NEXP * DDIM * HDIM * 2);  // 67.1 MB
  __bf16* hbuf      = (__bf16*)alloc((size_t)T_TOK * TOPK * HDIM * 2); // 67.1 MB
  int*    tk_idx    = (int*)  alloc((size_t)T_TOK * TOPK * 4);
  float*  tk_w      = (float*)alloc((size_t)T_TOK * TOPK * 4);
  int*    slot_tok  = (int*)  alloc((size_t)T_TOK * TOPK * 4);
  int*    inv_pos   = (int*)  alloc((size_t)T_TOK * TOPK * 4);
  int*    g_hist    = (int*)  alloc((size_t)CHUNKS * 64 * 4);
  int*    g_base    = (int*)  alloc((size_t)CHUNKS * 64 * 4);
  int*    offsets   = (int*)  alloc(512);
  __bf16* ybuf      = (__bf16*)ws;   // alias over wupT+xb+logits

  k_cvt_x<<<4096, 256, 0, stream>>>(x, xb);
  k_transpose_cvt<<<dim3(16, 32, 64), dim3(32, 8), 0, stream>>>(Wup,   wupT,   DDIM, HDIM);
  k_transpose_cvt<<<dim3(32, 16, 64), dim3(32, 8), 0, stream>>>(Wdown, wdownT, HDIM, DDIM);
  k_gate<<<T_TOK / 64, 256, 0, stream>>>(x, Wg, logits);
  k_topk<<<T_TOK / 4, 256, 0, stream>>>(logits, tk_idx, tk_w);
  k_hist<<<CHUNKS, 256, 0, stream>>>(tk_idx, g_hist);
  k_scan<<<1, 64, 0, stream>>>(g_hist, offsets, g_base);
  k_scatter<<<CHUNKS, 256, 0, stream>>>(tk_idx, g_base, slot_tok, inv_pos);
  // 256x256-tile grouped GEMMs (8 waves/block, swizzled LDS)
  k_gemm1<<<dim3(8, 2, 64), 512, 0, stream>>>(xb, wupT, offsets, slot_tok, hbuf);
  // group A: experts [0,32)
  k_gemm2<<<dim3(8, 4, 32), 512, 0, stream>>>(hbuf, wdownT, offsets, ybuf, 0);
  k_combine<<<T_TOK, 256, 0, stream>>>(ybuf, tk_idx, tk_w, inv_pos, offsets, out, 0, 32, 1);
  // group B: experts [32,64)
  k_gemm2<<<dim3(8, 4, 32), 512, 0, stream>>>(hbuf, wdownT, offsets, ybuf, 32);
  k_combine<<<T_TOK, 256, 0, stream>>>(ybuf, tk_idx, tk_w, inv_pos, offsets, out, 32, 64, 0);
}